// Round 5
// baseline (441.606 us; speedup 1.0000x reference)
//
#include <hip/hip_runtime.h>

// ---------------------------------------------------------------------------
// color_invariant_quadruplet: 3-hop label gather + 6-way equality embedding sum
//
// ROUND 5 = INSTRUMENTED ROUND. Structure = round-3 (best, 148.8us) with:
//   - table build folded into K1 (one fewer dispatch)
//   - write kernel replicated x4 via grid (idempotent identical writes) so it
//     exceeds the harness's 300us fill dispatches and appears in the rocprof
//     top-5 with its own dur/WRITE_SIZE/hbm_gbps. dur/4 = true write time.
// Decision rule (pre-committed):
//   write hbm_gbps >= ~6 TB/s -> write at roofline, attack gathers/gaps next
//   write hbm_gbps ~= 4.5 TB/s -> store-path surgery next (NT stores etc.)
// ---------------------------------------------------------------------------

#define N_FEAT 64

// K1: hop1, 4 g-edges/thread; blocks 0..15 also build the 64x64 table
// (reference left-to-right f32 add order -> bit-exact).
__global__ void hop1_table_kernel(const int* __restrict__ z,
                                  const int* __restrict__ src_g,
                                  const int* __restrict__ dst_g,
                                  unsigned short* __restrict__ zg,
                                  const float* __restrict__ e1,
                                  const float* __restrict__ e2,
                                  const float* __restrict__ e3,
                                  const float* __restrict__ e4,
                                  const float* __restrict__ e5,
                                  const float* __restrict__ e6,
                                  float* __restrict__ table,
                                  int n) {
    int i  = blockIdx.x * blockDim.x + threadIdx.x;
    int n4 = n >> 2;
    if (i < n4) {
        int4 s = ((const int4*)src_g)[i];
        int4 d = ((const int4*)dst_g)[i];
        unsigned zs0 = (unsigned)z[s.x], zd0 = (unsigned)z[d.x];
        unsigned zs1 = (unsigned)z[s.y], zd1 = (unsigned)z[d.y];
        unsigned zs2 = (unsigned)z[s.z], zd2 = (unsigned)z[d.z];
        unsigned zs3 = (unsigned)z[s.w], zd3 = (unsigned)z[d.w];
        unsigned r0 = (zs0 & 0xffu) | ((zd0 & 0xffu) << 8)
                    | ((zs1 & 0xffu) << 16) | ((zd1 & 0xffu) << 24);
        unsigned r1 = (zs2 & 0xffu) | ((zd2 & 0xffu) << 8)
                    | ((zs3 & 0xffu) << 16) | ((zd3 & 0xffu) << 24);
        ((uint2*)zg)[i] = make_uint2(r0, r1);
    } else {
        int e = (n4 << 2) + (i - n4);      // tail edges, scalar
        if (e < n) {
            zg[e] = (unsigned short)(((unsigned)z[src_g[e]] & 0xffu)
                                   | (((unsigned)z[dst_g[e]] & 0xffu) << 8));
        }
    }
    if (blockIdx.x < 16) {
        int idx = blockIdx.x * 256 + threadIdx.x;   // 0..4095
        int cmb = idx >> 6;
        int f   = idx & (N_FEAT - 1);
        float v = e1[((cmb >> 0) & 1) * N_FEAT + f];
        v      += e2[((cmb >> 1) & 1) * N_FEAT + f];
        v      += e3[((cmb >> 2) & 1) * N_FEAT + f];
        v      += e4[((cmb >> 3) & 1) * N_FEAT + f];
        v      += e5[((cmb >> 4) & 1) * N_FEAT + f];
        v      += e6[((cmb >> 5) & 1) * N_FEAT + f];
        table[idx] = v;
    }
}

// K2: hop2, 4 h-edges/thread. zh = z_src[src_h] | z_dst[dst_h]<<8.
__global__ void hop2_kernel(const unsigned short* __restrict__ zg,
                            const int* __restrict__ src_h,
                            const int* __restrict__ dst_h,
                            unsigned short* __restrict__ zh,
                            int n) {
    int i  = blockIdx.x * blockDim.x + threadIdx.x;
    int n4 = n >> 2;
    if (i < n4) {
        int4 s = ((const int4*)src_h)[i];
        int4 d = ((const int4*)dst_h)[i];
        unsigned a0 = zg[s.x], b0 = zg[d.x];
        unsigned a1 = zg[s.y], b1 = zg[d.y];
        unsigned a2 = zg[s.z], b2 = zg[d.z];
        unsigned a3 = zg[s.w], b3 = zg[d.w];
        unsigned r0 = (a0 & 0xffu) | (b0 & 0xff00u)
                    | ((a1 & 0xffu) << 16) | ((b1 & 0xff00u) << 16);
        unsigned r1 = (a2 & 0xffu) | (b2 & 0xff00u)
                    | ((a3 & 0xffu) << 16) | ((b3 & 0xff00u) << 16);
        ((uint2*)zh)[i] = make_uint2(r0, r1);
    } else {
        int e = (n4 << 2) + (i - n4);
        if (e < n) {
            unsigned a = zg[src_h[e]], b = zg[dst_h[e]];
            zh[e] = (unsigned short)((a & 0xffu) | (b & 0xff00u));
        }
    }
}

__device__ __forceinline__ unsigned combo6(unsigned p, unsigned q) {
    unsigned za = p & 0xffu, zc = p >> 8;
    unsigned zb = q & 0xffu, zd = q >> 8;
    return (unsigned)(za == zc)
         | ((unsigned)(za == zb) << 1)
         | ((unsigned)(zc == zb) << 2)
         | ((unsigned)(za == zd) << 3)
         | ((unsigned)(zc == zd) << 4)
         | ((unsigned)(zb == zd) << 5);
}

// K3a: combo, 4 i-edges/thread, packed uint store.
__global__ void combo_kernel(const unsigned short* __restrict__ zh,
                             const int* __restrict__ src_i,
                             const int* __restrict__ dst_i,
                             unsigned char* __restrict__ combo,
                             int n) {
    int i  = blockIdx.x * blockDim.x + threadIdx.x;
    int n4 = n >> 2;
    if (i < n4) {
        int4 s = ((const int4*)src_i)[i];
        int4 d = ((const int4*)dst_i)[i];
        unsigned p0 = zh[s.x], q0 = zh[d.x];
        unsigned p1 = zh[s.y], q1 = zh[d.y];
        unsigned p2 = zh[s.z], q2 = zh[d.z];
        unsigned p3 = zh[s.w], q3 = zh[d.w];
        unsigned c0 = combo6(p0, q0);
        unsigned c1 = combo6(p1, q1);
        unsigned c2 = combo6(p2, q2);
        unsigned c3 = combo6(p3, q3);
        ((unsigned*)combo)[i] = c0 | (c1 << 8) | (c2 << 16) | (c3 << 24);
    } else {
        int e = (n4 << 2) + (i - n4);
        if (e < n) combo[e] = (unsigned char)combo6(zh[src_i[e]], zh[dst_i[e]]);
    }
}

// K3b (instrumented): round-3 write kernel, replicated REP times via the grid.
// Pass-local block lb = blockIdx.x % nblkPerPass; all passes write identical
// bytes to identical addresses (idempotent). Passes are >=29K blocks apart in
// dispatch order -> lines evicted between passes -> true 4x HBM writes ->
// this dispatch's dur/4 = genuine single-pass write time.
__global__ __launch_bounds__(256)
void write_kernel(const unsigned char* __restrict__ combo,
                  const float* __restrict__ table,
                  float* __restrict__ out,
                  int nEdges, int nblkPerPass) {
    __shared__ float4 tbl[64 * 16];           // 64 rows x 16 float4
    int tid = threadIdx.x;
    const float4* t4 = (const float4*)table;
#pragma unroll
    for (int k = 0; k < 4; ++k)
        tbl[k * 256 + tid] = t4[k * 256 + tid];
    __syncthreads();

    int lb = blockIdx.x % nblkPerPass;

    long long total = (long long)nEdges * 16;           // total float4s
    long long base  = (long long)lb * 1024;             // this block's first f4

    long long f[4];
    int cb[4];
#pragma unroll
    for (int j = 0; j < 4; ++j) {
        f[j]  = base + j * 256 + tid;
        cb[j] = (f[j] < total) ? (int)combo[f[j] >> 4] : 0;
    }
#pragma unroll
    for (int j = 0; j < 4; ++j) {
        if (f[j] < total) {
            int c = (int)(f[j] & 15);
            ((float4*)out)[f[j]] = tbl[cb[j] * 16 + c];
        }
    }
}

extern "C" void kernel_launch(void* const* d_in, const int* in_sizes, int n_in,
                              void* d_out, int out_size, void* d_ws, size_t ws_size,
                              hipStream_t stream) {
    const int* z     = (const int*)d_in[0];
    const int* src_g = (const int*)d_in[1];
    const int* dst_g = (const int*)d_in[2];
    const int* src_h = (const int*)d_in[3];
    const int* dst_h = (const int*)d_in[4];
    const int* src_i = (const int*)d_in[5];
    const int* dst_i = (const int*)d_in[6];
    const float* e1  = (const float*)d_in[7];
    const float* e2  = (const float*)d_in[8];
    const float* e3  = (const float*)d_in[9];
    const float* e4  = (const float*)d_in[10];
    const float* e5  = (const float*)d_in[11];
    const float* e6  = (const float*)d_in[12];

    int E_G = in_sizes[1];
    int E_H = in_sizes[3];
    int E_I = in_sizes[5];

    // Workspace: table | zg | zh | combo (256B-aligned)
    char* ws = (char*)d_ws;
    float* table = (float*)ws;
    size_t off   = 64 * N_FEAT * sizeof(float);
    unsigned short* zg = (unsigned short*)(ws + off);
    off += (size_t)E_G * sizeof(unsigned short);
    off  = (off + 255) & ~(size_t)255;
    unsigned short* zh = (unsigned short*)(ws + off);
    off += (size_t)E_H * sizeof(unsigned short);
    off  = (off + 255) & ~(size_t)255;
    unsigned char* combo = (unsigned char*)(ws + off);

    float* out = (float*)d_out;

    // K1: hop1 + table build
    {
        int n4 = E_G >> 2, nth = n4 + (E_G - (n4 << 2));
        int blocks = (nth + 255) / 256;
        if (blocks < 16) blocks = 16;
        hop1_table_kernel<<<blocks, 256, 0, stream>>>(z, src_g, dst_g, zg,
                                                      e1, e2, e3, e4, e5, e6,
                                                      table, E_G);
    }
    // K2
    {
        int n4 = E_H >> 2, nth = n4 + (E_H - (n4 << 2));
        hop2_kernel<<<(nth + 255) / 256, 256, 0, stream>>>(zg, src_h, dst_h, zh, E_H);
    }
    // K3a
    {
        int n4 = E_I >> 2, nth = n4 + (E_I - (n4 << 2));
        combo_kernel<<<(nth + 255) / 256, 256, 0, stream>>>(zh, src_i, dst_i, combo, E_I);
    }
    // K3b instrumented: REP=4 passes in one dispatch (idempotent)
    {
        const int REP = 4;
        int nblkPerPass = (E_I + 63) / 64;        // 64 edges per block
        write_kernel<<<nblkPerPass * REP, 256, 0, stream>>>(combo, table, out,
                                                            E_I, nblkPerPass);
    }
}

// Round 6
// 157.621 us; speedup vs baseline: 2.8017x; 2.8017x over previous
//
#include <hip/hip_runtime.h>

// ---------------------------------------------------------------------------
// color_invariant_quadruplet: 3-hop label gather + 6-way equality embedding sum
//
// The 6 equality bits take 64 combinations; each maps to a fixed 64-float row.
// Pipeline (4 one-shot kernels):
//   K1 : hop1 packed labels (4 edges/thread) + table build (blocks 0..15)
//   K2 : hop2 packed (z_ss, z_dd)            (4 edges/thread)
//   K3a: per i-edge 6-bit combo byte         (4 edges/thread, uint store)
//   K3b: streaming write, 256 edges/block (64 KB out). Combo chunk (256 B)
//        and table (16 KB) staged to LDS; ONE barrier; then 16 independent
//        coalesced 1KB wave-stores per thread-slot sourced ONLY from LDS --
//        no vmcnt waits in the store stream (round-5 measurement: old write
//        ran 5.15 TB/s vs 6.8 fill; per-block head + combo-load vmcnt FIFO
//        blamed). Nontemporal stores (output never re-read).
// Round-5 instrumentation established: write ~100us, gathers+gaps ~43us.
// ---------------------------------------------------------------------------

#define N_FEAT 64

typedef float f4 __attribute__((ext_vector_type(4)));

// K1: hop1, 4 g-edges/thread; blocks 0..15 also build the 64x64 table
// (reference left-to-right f32 add order -> bit-exact).
__global__ void hop1_table_kernel(const int* __restrict__ z,
                                  const int* __restrict__ src_g,
                                  const int* __restrict__ dst_g,
                                  unsigned short* __restrict__ zg,
                                  const float* __restrict__ e1,
                                  const float* __restrict__ e2,
                                  const float* __restrict__ e3,
                                  const float* __restrict__ e4,
                                  const float* __restrict__ e5,
                                  const float* __restrict__ e6,
                                  float* __restrict__ table,
                                  int n) {
    int i  = blockIdx.x * blockDim.x + threadIdx.x;
    int n4 = n >> 2;
    if (i < n4) {
        int4 s = ((const int4*)src_g)[i];
        int4 d = ((const int4*)dst_g)[i];
        unsigned zs0 = (unsigned)z[s.x], zd0 = (unsigned)z[d.x];
        unsigned zs1 = (unsigned)z[s.y], zd1 = (unsigned)z[d.y];
        unsigned zs2 = (unsigned)z[s.z], zd2 = (unsigned)z[d.z];
        unsigned zs3 = (unsigned)z[s.w], zd3 = (unsigned)z[d.w];
        unsigned r0 = (zs0 & 0xffu) | ((zd0 & 0xffu) << 8)
                    | ((zs1 & 0xffu) << 16) | ((zd1 & 0xffu) << 24);
        unsigned r1 = (zs2 & 0xffu) | ((zd2 & 0xffu) << 8)
                    | ((zs3 & 0xffu) << 16) | ((zd3 & 0xffu) << 24);
        ((uint2*)zg)[i] = make_uint2(r0, r1);
    } else {
        int e = (n4 << 2) + (i - n4);      // tail edges, scalar
        if (e < n) {
            zg[e] = (unsigned short)(((unsigned)z[src_g[e]] & 0xffu)
                                   | (((unsigned)z[dst_g[e]] & 0xffu) << 8));
        }
    }
    if (blockIdx.x < 16) {
        int idx = blockIdx.x * 256 + threadIdx.x;   // 0..4095
        int cmb = idx >> 6;
        int f   = idx & (N_FEAT - 1);
        float v = e1[((cmb >> 0) & 1) * N_FEAT + f];
        v      += e2[((cmb >> 1) & 1) * N_FEAT + f];
        v      += e3[((cmb >> 2) & 1) * N_FEAT + f];
        v      += e4[((cmb >> 3) & 1) * N_FEAT + f];
        v      += e5[((cmb >> 4) & 1) * N_FEAT + f];
        v      += e6[((cmb >> 5) & 1) * N_FEAT + f];
        table[idx] = v;
    }
}

// K2: hop2, 4 h-edges/thread. zh = z_src[src_h] | z_dst[dst_h]<<8.
__global__ void hop2_kernel(const unsigned short* __restrict__ zg,
                            const int* __restrict__ src_h,
                            const int* __restrict__ dst_h,
                            unsigned short* __restrict__ zh,
                            int n) {
    int i  = blockIdx.x * blockDim.x + threadIdx.x;
    int n4 = n >> 2;
    if (i < n4) {
        int4 s = ((const int4*)src_h)[i];
        int4 d = ((const int4*)dst_h)[i];
        unsigned a0 = zg[s.x], b0 = zg[d.x];
        unsigned a1 = zg[s.y], b1 = zg[d.y];
        unsigned a2 = zg[s.z], b2 = zg[d.z];
        unsigned a3 = zg[s.w], b3 = zg[d.w];
        unsigned r0 = (a0 & 0xffu) | (b0 & 0xff00u)
                    | ((a1 & 0xffu) << 16) | ((b1 & 0xff00u) << 16);
        unsigned r1 = (a2 & 0xffu) | (b2 & 0xff00u)
                    | ((a3 & 0xffu) << 16) | ((b3 & 0xff00u) << 16);
        ((uint2*)zh)[i] = make_uint2(r0, r1);
    } else {
        int e = (n4 << 2) + (i - n4);
        if (e < n) {
            unsigned a = zg[src_h[e]], b = zg[dst_h[e]];
            zh[e] = (unsigned short)((a & 0xffu) | (b & 0xff00u));
        }
    }
}

__device__ __forceinline__ unsigned combo6(unsigned p, unsigned q) {
    unsigned za = p & 0xffu, zc = p >> 8;
    unsigned zb = q & 0xffu, zd = q >> 8;
    return (unsigned)(za == zc)
         | ((unsigned)(za == zb) << 1)
         | ((unsigned)(zc == zb) << 2)
         | ((unsigned)(za == zd) << 3)
         | ((unsigned)(zc == zd) << 4)
         | ((unsigned)(zb == zd) << 5);
}

// K3a: combo, 4 i-edges/thread, packed uint store.
__global__ void combo_kernel(const unsigned short* __restrict__ zh,
                             const int* __restrict__ src_i,
                             const int* __restrict__ dst_i,
                             unsigned char* __restrict__ combo,
                             int n) {
    int i  = blockIdx.x * blockDim.x + threadIdx.x;
    int n4 = n >> 2;
    if (i < n4) {
        int4 s = ((const int4*)src_i)[i];
        int4 d = ((const int4*)dst_i)[i];
        unsigned p0 = zh[s.x], q0 = zh[d.x];
        unsigned p1 = zh[s.y], q1 = zh[d.y];
        unsigned p2 = zh[s.z], q2 = zh[d.z];
        unsigned p3 = zh[s.w], q3 = zh[d.w];
        unsigned c0 = combo6(p0, q0);
        unsigned c1 = combo6(p1, q1);
        unsigned c2 = combo6(p2, q2);
        unsigned c3 = combo6(p3, q3);
        ((unsigned*)combo)[i] = c0 | (c1 << 8) | (c2 << 16) | (c3 << 24);
    } else {
        int e = (n4 << 2) + (i - n4);
        if (e < n) combo[e] = (unsigned char)combo6(zh[src_i[e]], zh[dst_i[e]]);
    }
}

// K3b: streaming write, 256 edges (64 KB output) per 256-thread block.
// Stage combo chunk (256 B, coalesced) + table (16 KB) to LDS, one barrier,
// then 16 independent nontemporal 1KB wave-stores per thread-slot; all store
// data comes from LDS (lgkmcnt waits only -- the store stream never waits on
// vmcnt). LDS 16.25 KB -> 8 blocks/CU co-resident hides the per-block head.
__global__ __launch_bounds__(256)
void write_kernel(const unsigned char* __restrict__ combo,
                  const float* __restrict__ table,
                  float* __restrict__ out,
                  int nEdges) {
    __shared__ f4 tbl[64 * 16];            // 64 rows x 16 f4
    __shared__ unsigned char cmb[256];     // this block's combo bytes
    const int tid = threadIdx.x;
    const long long e0 = (long long)blockIdx.x * 256;

    // stage combo chunk (64 coalesced uint loads; e0 is 256B-aligned offset)
    int nb = nEdges - (int)e0; if (nb > 256) nb = 256;   // edges in this block
    if (tid < 64 && tid * 4 < nb)
        ((unsigned*)cmb)[tid] = ((const unsigned*)(combo + e0))[tid];
    // stage table
    const f4* t4 = (const f4*)table;
#pragma unroll
    for (int k = 0; k < 4; ++k)
        tbl[k * 256 + tid] = t4[k * 256 + tid];
    __syncthreads();

    // 4096 f4 per block; slot k: thread tid writes f4 (base + k*256 + tid).
    // f & 15 == tid & 15 (base is a multiple of 4096).
    const long long base  = e0 * 16;
    const long long total = (long long)nEdges * 16;
    const int c = tid & 15;
#pragma unroll
    for (int k = 0; k < 16; ++k) {
        long long f = base + k * 256 + tid;
        if (f < total) {
            int le = k * 16 + (tid >> 4);              // local edge 0..255
            f4 v = tbl[(int)cmb[le] * 16 + c];
            __builtin_nontemporal_store(v, (f4*)out + f);
        }
    }
}

extern "C" void kernel_launch(void* const* d_in, const int* in_sizes, int n_in,
                              void* d_out, int out_size, void* d_ws, size_t ws_size,
                              hipStream_t stream) {
    const int* z     = (const int*)d_in[0];
    const int* src_g = (const int*)d_in[1];
    const int* dst_g = (const int*)d_in[2];
    const int* src_h = (const int*)d_in[3];
    const int* dst_h = (const int*)d_in[4];
    const int* src_i = (const int*)d_in[5];
    const int* dst_i = (const int*)d_in[6];
    const float* e1  = (const float*)d_in[7];
    const float* e2  = (const float*)d_in[8];
    const float* e3  = (const float*)d_in[9];
    const float* e4  = (const float*)d_in[10];
    const float* e5  = (const float*)d_in[11];
    const float* e6  = (const float*)d_in[12];

    int E_G = in_sizes[1];
    int E_H = in_sizes[3];
    int E_I = in_sizes[5];

    // Workspace: table | zg | zh | combo (256B-aligned, combo padded)
    char* ws = (char*)d_ws;
    float* table = (float*)ws;
    size_t off   = 64 * N_FEAT * sizeof(float);
    unsigned short* zg = (unsigned short*)(ws + off);
    off += (size_t)E_G * sizeof(unsigned short);
    off  = (off + 255) & ~(size_t)255;
    unsigned short* zh = (unsigned short*)(ws + off);
    off += (size_t)E_H * sizeof(unsigned short);
    off  = (off + 255) & ~(size_t)255;
    unsigned char* combo = (unsigned char*)(ws + off);

    float* out = (float*)d_out;

    // K1: hop1 + table build
    {
        int n4 = E_G >> 2, nth = n4 + (E_G - (n4 << 2));
        int blocks = (nth + 255) / 256;
        if (blocks < 16) blocks = 16;
        hop1_table_kernel<<<blocks, 256, 0, stream>>>(z, src_g, dst_g, zg,
                                                      e1, e2, e3, e4, e5, e6,
                                                      table, E_G);
    }
    // K2
    {
        int n4 = E_H >> 2, nth = n4 + (E_H - (n4 << 2));
        hop2_kernel<<<(nth + 255) / 256, 256, 0, stream>>>(zg, src_h, dst_h, zh, E_H);
    }
    // K3a
    {
        int n4 = E_I >> 2, nth = n4 + (E_I - (n4 << 2));
        combo_kernel<<<(nth + 255) / 256, 256, 0, stream>>>(zh, src_i, dst_i, combo, E_I);
    }
    // K3b: 256 edges per block
    {
        int blocks = (E_I + 255) / 256;
        write_kernel<<<blocks, 256, 0, stream>>>(combo, table, out, E_I);
    }
}

// Round 7
// 149.786 us; speedup vs baseline: 2.9482x; 1.0523x over previous
//
#include <hip/hip_runtime.h>

// ---------------------------------------------------------------------------
// color_invariant_quadruplet: 3-hop label gather + 6-way equality embedding sum
//
// The 6 equality bits take 64 combinations; each maps to a fixed 64-float row.
// Pipeline (4 one-shot kernels):
//   K1 : hop1 packed labels (4 edges/thread) + table build (blocks 0..15)
//   K2 : hop2 packed (z_ss, z_dd)            (4 edges/thread)
//   K3a: per i-edge 6-bit combo byte         (4 edges/thread, uint store)
//   K3b: streaming write, 256 edges/block (64 KB out). Combo chunk (256 B)
//        and table (16 KB) staged to LDS; ONE barrier; 16 independent
//        coalesced 1KB wave-stores per thread-slot sourced ONLY from LDS.
//
// Round 7 change: REVERT nontemporal stores -> plain stores (round 6's only
// plausible regression cause; the 6.8 TB/s fill kernel uses plain stores).
// Everything else identical to round 6 to isolate the NT effect.
// Round-5 instrumentation: write ~100us @5.15 TB/s, gathers+gaps ~43us.
// ---------------------------------------------------------------------------

#define N_FEAT 64

typedef float f4 __attribute__((ext_vector_type(4)));

// K1: hop1, 4 g-edges/thread; blocks 0..15 also build the 64x64 table
// (reference left-to-right f32 add order -> bit-exact).
__global__ void hop1_table_kernel(const int* __restrict__ z,
                                  const int* __restrict__ src_g,
                                  const int* __restrict__ dst_g,
                                  unsigned short* __restrict__ zg,
                                  const float* __restrict__ e1,
                                  const float* __restrict__ e2,
                                  const float* __restrict__ e3,
                                  const float* __restrict__ e4,
                                  const float* __restrict__ e5,
                                  const float* __restrict__ e6,
                                  float* __restrict__ table,
                                  int n) {
    int i  = blockIdx.x * blockDim.x + threadIdx.x;
    int n4 = n >> 2;
    if (i < n4) {
        int4 s = ((const int4*)src_g)[i];
        int4 d = ((const int4*)dst_g)[i];
        unsigned zs0 = (unsigned)z[s.x], zd0 = (unsigned)z[d.x];
        unsigned zs1 = (unsigned)z[s.y], zd1 = (unsigned)z[d.y];
        unsigned zs2 = (unsigned)z[s.z], zd2 = (unsigned)z[d.z];
        unsigned zs3 = (unsigned)z[s.w], zd3 = (unsigned)z[d.w];
        unsigned r0 = (zs0 & 0xffu) | ((zd0 & 0xffu) << 8)
                    | ((zs1 & 0xffu) << 16) | ((zd1 & 0xffu) << 24);
        unsigned r1 = (zs2 & 0xffu) | ((zd2 & 0xffu) << 8)
                    | ((zs3 & 0xffu) << 16) | ((zd3 & 0xffu) << 24);
        ((uint2*)zg)[i] = make_uint2(r0, r1);
    } else {
        int e = (n4 << 2) + (i - n4);      // tail edges, scalar
        if (e < n) {
            zg[e] = (unsigned short)(((unsigned)z[src_g[e]] & 0xffu)
                                   | (((unsigned)z[dst_g[e]] & 0xffu) << 8));
        }
    }
    if (blockIdx.x < 16) {
        int idx = blockIdx.x * 256 + threadIdx.x;   // 0..4095
        int cmb = idx >> 6;
        int f   = idx & (N_FEAT - 1);
        float v = e1[((cmb >> 0) & 1) * N_FEAT + f];
        v      += e2[((cmb >> 1) & 1) * N_FEAT + f];
        v      += e3[((cmb >> 2) & 1) * N_FEAT + f];
        v      += e4[((cmb >> 3) & 1) * N_FEAT + f];
        v      += e5[((cmb >> 4) & 1) * N_FEAT + f];
        v      += e6[((cmb >> 5) & 1) * N_FEAT + f];
        table[idx] = v;
    }
}

// K2: hop2, 4 h-edges/thread. zh = z_src[src_h] | z_dst[dst_h]<<8.
__global__ void hop2_kernel(const unsigned short* __restrict__ zg,
                            const int* __restrict__ src_h,
                            const int* __restrict__ dst_h,
                            unsigned short* __restrict__ zh,
                            int n) {
    int i  = blockIdx.x * blockDim.x + threadIdx.x;
    int n4 = n >> 2;
    if (i < n4) {
        int4 s = ((const int4*)src_h)[i];
        int4 d = ((const int4*)dst_h)[i];
        unsigned a0 = zg[s.x], b0 = zg[d.x];
        unsigned a1 = zg[s.y], b1 = zg[d.y];
        unsigned a2 = zg[s.z], b2 = zg[d.z];
        unsigned a3 = zg[s.w], b3 = zg[d.w];
        unsigned r0 = (a0 & 0xffu) | (b0 & 0xff00u)
                    | ((a1 & 0xffu) << 16) | ((b1 & 0xff00u) << 16);
        unsigned r1 = (a2 & 0xffu) | (b2 & 0xff00u)
                    | ((a3 & 0xffu) << 16) | ((b3 & 0xff00u) << 16);
        ((uint2*)zh)[i] = make_uint2(r0, r1);
    } else {
        int e = (n4 << 2) + (i - n4);
        if (e < n) {
            unsigned a = zg[src_h[e]], b = zg[dst_h[e]];
            zh[e] = (unsigned short)((a & 0xffu) | (b & 0xff00u));
        }
    }
}

__device__ __forceinline__ unsigned combo6(unsigned p, unsigned q) {
    unsigned za = p & 0xffu, zc = p >> 8;
    unsigned zb = q & 0xffu, zd = q >> 8;
    return (unsigned)(za == zc)
         | ((unsigned)(za == zb) << 1)
         | ((unsigned)(zc == zb) << 2)
         | ((unsigned)(za == zd) << 3)
         | ((unsigned)(zc == zd) << 4)
         | ((unsigned)(zb == zd) << 5);
}

// K3a: combo, 4 i-edges/thread, packed uint store.
__global__ void combo_kernel(const unsigned short* __restrict__ zh,
                             const int* __restrict__ src_i,
                             const int* __restrict__ dst_i,
                             unsigned char* __restrict__ combo,
                             int n) {
    int i  = blockIdx.x * blockDim.x + threadIdx.x;
    int n4 = n >> 2;
    if (i < n4) {
        int4 s = ((const int4*)src_i)[i];
        int4 d = ((const int4*)dst_i)[i];
        unsigned p0 = zh[s.x], q0 = zh[d.x];
        unsigned p1 = zh[s.y], q1 = zh[d.y];
        unsigned p2 = zh[s.z], q2 = zh[d.z];
        unsigned p3 = zh[s.w], q3 = zh[d.w];
        unsigned c0 = combo6(p0, q0);
        unsigned c1 = combo6(p1, q1);
        unsigned c2 = combo6(p2, q2);
        unsigned c3 = combo6(p3, q3);
        ((unsigned*)combo)[i] = c0 | (c1 << 8) | (c2 << 16) | (c3 << 24);
    } else {
        int e = (n4 << 2) + (i - n4);
        if (e < n) combo[e] = (unsigned char)combo6(zh[src_i[e]], zh[dst_i[e]]);
    }
}

// K3b: streaming write, 256 edges (64 KB output) per 256-thread block.
// Stage combo chunk (256 B, coalesced) + table (16 KB) to LDS, one barrier,
// then 16 independent PLAIN 1KB wave-stores per thread-slot; all store data
// comes from LDS (lgkmcnt waits only -- the store stream never waits on
// vmcnt). LDS 16.25 KB -> 8 blocks/CU co-resident hides the per-block head.
__global__ __launch_bounds__(256)
void write_kernel(const unsigned char* __restrict__ combo,
                  const float* __restrict__ table,
                  float* __restrict__ out,
                  int nEdges) {
    __shared__ f4 tbl[64 * 16];            // 64 rows x 16 f4
    __shared__ unsigned char cmb[256];     // this block's combo bytes
    const int tid = threadIdx.x;
    const long long e0 = (long long)blockIdx.x * 256;

    // stage combo chunk (64 coalesced uint loads; e0 is 256B-aligned offset)
    int nb = nEdges - (int)e0; if (nb > 256) nb = 256;   // edges in this block
    if (tid < 64 && tid * 4 < nb)
        ((unsigned*)cmb)[tid] = ((const unsigned*)(combo + e0))[tid];
    // stage table
    const f4* t4 = (const f4*)table;
#pragma unroll
    for (int k = 0; k < 4; ++k)
        tbl[k * 256 + tid] = t4[k * 256 + tid];
    __syncthreads();

    // 4096 f4 per block; slot k: thread tid writes f4 (base + k*256 + tid).
    // f & 15 == tid & 15 (base is a multiple of 4096).
    const long long base  = e0 * 16;
    const long long total = (long long)nEdges * 16;
    const int c = tid & 15;
#pragma unroll
    for (int k = 0; k < 16; ++k) {
        long long f = base + k * 256 + tid;
        if (f < total) {
            int le = k * 16 + (tid >> 4);              // local edge 0..255
            ((f4*)out)[f] = tbl[(int)cmb[le] * 16 + c];
        }
    }
}

extern "C" void kernel_launch(void* const* d_in, const int* in_sizes, int n_in,
                              void* d_out, int out_size, void* d_ws, size_t ws_size,
                              hipStream_t stream) {
    const int* z     = (const int*)d_in[0];
    const int* src_g = (const int*)d_in[1];
    const int* dst_g = (const int*)d_in[2];
    const int* src_h = (const int*)d_in[3];
    const int* dst_h = (const int*)d_in[4];
    const int* src_i = (const int*)d_in[5];
    const int* dst_i = (const int*)d_in[6];
    const float* e1  = (const float*)d_in[7];
    const float* e2  = (const float*)d_in[8];
    const float* e3  = (const float*)d_in[9];
    const float* e4  = (const float*)d_in[10];
    const float* e5  = (const float*)d_in[11];
    const float* e6  = (const float*)d_in[12];

    int E_G = in_sizes[1];
    int E_H = in_sizes[3];
    int E_I = in_sizes[5];

    // Workspace: table | zg | zh | combo (256B-aligned)
    char* ws = (char*)d_ws;
    float* table = (float*)ws;
    size_t off   = 64 * N_FEAT * sizeof(float);
    unsigned short* zg = (unsigned short*)(ws + off);
    off += (size_t)E_G * sizeof(unsigned short);
    off  = (off + 255) & ~(size_t)255;
    unsigned short* zh = (unsigned short*)(ws + off);
    off += (size_t)E_H * sizeof(unsigned short);
    off  = (off + 255) & ~(size_t)255;
    unsigned char* combo = (unsigned char*)(ws + off);

    float* out = (float*)d_out;

    // K1: hop1 + table build
    {
        int n4 = E_G >> 2, nth = n4 + (E_G - (n4 << 2));
        int blocks = (nth + 255) / 256;
        if (blocks < 16) blocks = 16;
        hop1_table_kernel<<<blocks, 256, 0, stream>>>(z, src_g, dst_g, zg,
                                                      e1, e2, e3, e4, e5, e6,
                                                      table, E_G);
    }
    // K2
    {
        int n4 = E_H >> 2, nth = n4 + (E_H - (n4 << 2));
        hop2_kernel<<<(nth + 255) / 256, 256, 0, stream>>>(zg, src_h, dst_h, zh, E_H);
    }
    // K3a
    {
        int n4 = E_I >> 2, nth = n4 + (E_I - (n4 << 2));
        combo_kernel<<<(nth + 255) / 256, 256, 0, stream>>>(zh, src_i, dst_i, combo, E_I);
    }
    // K3b: 256 edges per block
    {
        int blocks = (E_I + 255) / 256;
        write_kernel<<<blocks, 256, 0, stream>>>(combo, table, out, E_I);
    }
}

// Round 8
// 148.614 us; speedup vs baseline: 2.9715x; 1.0079x over previous
//
#include <hip/hip_runtime.h>

// ---------------------------------------------------------------------------
// color_invariant_quadruplet: 3-hop label gather + 6-way equality embedding sum
//
// The 6 equality bits take 64 combinations; each maps to a fixed 64-float row.
// Pipeline (4 one-shot kernels):
//   K1 : hop1 packed labels (4 edges/thread) + table build (blocks 0..15)
//   K2 : hop2 packed (z_ss, z_dd)            (4 edges/thread)
//   K3a: per i-edge 6-bit combo byte         (4 edges/thread, uint store)
//   K3b: streaming write in the FILL-KERNEL REGIME (round 8 change):
//        489 blocks (~2/CU, ~25% occupancy), each block owns a contiguous
//        1 MB output region; each WAVE owns a contiguous 256 KB sequential
//        stream (256 x 1KB stores). Store loop has NO global loads (combo
//        slice + table staged in LDS) -> no vmcnt waits. Rationale: fill
//        kernel does 6.8 TB/s at 11% occupancy / ~1K long streams; r3 & r7
//        both did 5.15 TB/s at 80% occupancy / ~8K short streams, and were
//        neutral to store-depth -> test stream-count/occupancy as the limiter.
// Round-5 instrumentation: write ~100us @5.15 TB/s, gathers+gaps ~43-50us.
// ---------------------------------------------------------------------------

#define N_FEAT 64
#define WEPB   4096   // edges per write-block (1 MB output, 4 KB combo slice)

typedef float f4 __attribute__((ext_vector_type(4)));

// K1: hop1, 4 g-edges/thread; blocks 0..15 also build the 64x64 table
// (reference left-to-right f32 add order -> bit-exact).
__global__ void hop1_table_kernel(const int* __restrict__ z,
                                  const int* __restrict__ src_g,
                                  const int* __restrict__ dst_g,
                                  unsigned short* __restrict__ zg,
                                  const float* __restrict__ e1,
                                  const float* __restrict__ e2,
                                  const float* __restrict__ e3,
                                  const float* __restrict__ e4,
                                  const float* __restrict__ e5,
                                  const float* __restrict__ e6,
                                  float* __restrict__ table,
                                  int n) {
    int i  = blockIdx.x * blockDim.x + threadIdx.x;
    int n4 = n >> 2;
    if (i < n4) {
        int4 s = ((const int4*)src_g)[i];
        int4 d = ((const int4*)dst_g)[i];
        unsigned zs0 = (unsigned)z[s.x], zd0 = (unsigned)z[d.x];
        unsigned zs1 = (unsigned)z[s.y], zd1 = (unsigned)z[d.y];
        unsigned zs2 = (unsigned)z[s.z], zd2 = (unsigned)z[d.z];
        unsigned zs3 = (unsigned)z[s.w], zd3 = (unsigned)z[d.w];
        unsigned r0 = (zs0 & 0xffu) | ((zd0 & 0xffu) << 8)
                    | ((zs1 & 0xffu) << 16) | ((zd1 & 0xffu) << 24);
        unsigned r1 = (zs2 & 0xffu) | ((zd2 & 0xffu) << 8)
                    | ((zs3 & 0xffu) << 16) | ((zd3 & 0xffu) << 24);
        ((uint2*)zg)[i] = make_uint2(r0, r1);
    } else {
        int e = (n4 << 2) + (i - n4);      // tail edges, scalar
        if (e < n) {
            zg[e] = (unsigned short)(((unsigned)z[src_g[e]] & 0xffu)
                                   | (((unsigned)z[dst_g[e]] & 0xffu) << 8));
        }
    }
    if (blockIdx.x < 16) {
        int idx = blockIdx.x * 256 + threadIdx.x;   // 0..4095
        int cmb = idx >> 6;
        int f   = idx & (N_FEAT - 1);
        float v = e1[((cmb >> 0) & 1) * N_FEAT + f];
        v      += e2[((cmb >> 1) & 1) * N_FEAT + f];
        v      += e3[((cmb >> 2) & 1) * N_FEAT + f];
        v      += e4[((cmb >> 3) & 1) * N_FEAT + f];
        v      += e5[((cmb >> 4) & 1) * N_FEAT + f];
        v      += e6[((cmb >> 5) & 1) * N_FEAT + f];
        table[idx] = v;
    }
}

// K2: hop2, 4 h-edges/thread. zh = z_src[src_h] | z_dst[dst_h]<<8.
__global__ void hop2_kernel(const unsigned short* __restrict__ zg,
                            const int* __restrict__ src_h,
                            const int* __restrict__ dst_h,
                            unsigned short* __restrict__ zh,
                            int n) {
    int i  = blockIdx.x * blockDim.x + threadIdx.x;
    int n4 = n >> 2;
    if (i < n4) {
        int4 s = ((const int4*)src_h)[i];
        int4 d = ((const int4*)dst_h)[i];
        unsigned a0 = zg[s.x], b0 = zg[d.x];
        unsigned a1 = zg[s.y], b1 = zg[d.y];
        unsigned a2 = zg[s.z], b2 = zg[d.z];
        unsigned a3 = zg[s.w], b3 = zg[d.w];
        unsigned r0 = (a0 & 0xffu) | (b0 & 0xff00u)
                    | ((a1 & 0xffu) << 16) | ((b1 & 0xff00u) << 16);
        unsigned r1 = (a2 & 0xffu) | (b2 & 0xff00u)
                    | ((a3 & 0xffu) << 16) | ((b3 & 0xff00u) << 16);
        ((uint2*)zh)[i] = make_uint2(r0, r1);
    } else {
        int e = (n4 << 2) + (i - n4);
        if (e < n) {
            unsigned a = zg[src_h[e]], b = zg[dst_h[e]];
            zh[e] = (unsigned short)((a & 0xffu) | (b & 0xff00u));
        }
    }
}

__device__ __forceinline__ unsigned combo6(unsigned p, unsigned q) {
    unsigned za = p & 0xffu, zc = p >> 8;
    unsigned zb = q & 0xffu, zd = q >> 8;
    return (unsigned)(za == zc)
         | ((unsigned)(za == zb) << 1)
         | ((unsigned)(zc == zb) << 2)
         | ((unsigned)(za == zd) << 3)
         | ((unsigned)(zc == zd) << 4)
         | ((unsigned)(zb == zd) << 5);
}

// K3a: combo, 4 i-edges/thread, packed uint store.
__global__ void combo_kernel(const unsigned short* __restrict__ zh,
                             const int* __restrict__ src_i,
                             const int* __restrict__ dst_i,
                             unsigned char* __restrict__ combo,
                             int n) {
    int i  = blockIdx.x * blockDim.x + threadIdx.x;
    int n4 = n >> 2;
    if (i < n4) {
        int4 s = ((const int4*)src_i)[i];
        int4 d = ((const int4*)dst_i)[i];
        unsigned p0 = zh[s.x], q0 = zh[d.x];
        unsigned p1 = zh[s.y], q1 = zh[d.y];
        unsigned p2 = zh[s.z], q2 = zh[d.z];
        unsigned p3 = zh[s.w], q3 = zh[d.w];
        unsigned c0 = combo6(p0, q0);
        unsigned c1 = combo6(p1, q1);
        unsigned c2 = combo6(p2, q2);
        unsigned c3 = combo6(p3, q3);
        ((unsigned*)combo)[i] = c0 | (c1 << 8) | (c2 << 16) | (c3 << 24);
    } else {
        int e = (n4 << 2) + (i - n4);
        if (e < n) combo[e] = (unsigned char)combo6(zh[src_i[e]], zh[dst_i[e]]);
    }
}

// K3b: fill-regime streaming write. WEPB=4096 edges (1 MB out) per block,
// ~489 blocks (~2/CU). Stage combo slice (4 KB) + table (16 KB) to LDS,
// one barrier, then each wave emits a 256 KB contiguous sequential store
// stream: 256 x {ds_read combo byte, ds_read_b128 table row, 1KB wave-store}.
// No global loads in the loop -> stores never wait on vmcnt.
__global__ __launch_bounds__(256)
void write_kernel(const unsigned char* __restrict__ combo,
                  const float* __restrict__ table,
                  float* __restrict__ out,
                  int nEdges) {
    __shared__ f4 tbl[64 * 16];                 // 16 KB
    __shared__ unsigned char cmb[WEPB];         // 4 KB
    const int tid = threadIdx.x;
    const long long e0 = (long long)blockIdx.x * WEPB;
    int nb = nEdges - (int)e0; if (nb > WEPB) nb = WEPB;

    // stage combo slice (coalesced uint loads, 4/thread)
    {
        const unsigned* src = (const unsigned*)(combo + e0);
        unsigned*       dst = (unsigned*)cmb;
        int nw = (nb + 3) >> 2;
#pragma unroll
        for (int k = 0; k < WEPB / 4 / 256; ++k) {      // 4
            int idx = k * 256 + tid;
            if (idx < nw) dst[idx] = src[idx];
        }
    }
    // stage table (4 f4/thread, coalesced)
    const f4* t4 = (const f4*)table;
#pragma unroll
    for (int k = 0; k < 4; ++k)
        tbl[k * 256 + tid] = t4[k * 256 + tid];
    __syncthreads();

    // wave w owns f4s [e0*16 + w*16384, +16384) -- contiguous 256 KB.
    // iteration i: f = fBase + i*64; le = w*1024 + i*4 + (lane>>4);
    // c = lane&15 (all bases are multiples of 16).
    const int  w      = tid >> 6;
    const int  lane   = tid & 63;
    const int  c      = lane & 15;
    const int  leBase = w * (WEPB / 4) + (lane >> 4);
    const long long fBase = e0 * 16 + (long long)w * (WEPB * 16 / 4) + lane;
    constexpr int ITER = WEPB * 16 / 4 / 64;            // 256

    if (nb == WEPB) {
        // full block: unguarded hot loop
#pragma unroll 4
        for (int i = 0; i < ITER; ++i) {
            int le = leBase + i * 4;
            ((f4*)out)[fBase + (long long)i * 64] = tbl[(int)cmb[le] * 16 + c];
        }
    } else {
        const long long total = (long long)nEdges * 16;
#pragma unroll 4
        for (int i = 0; i < ITER; ++i) {
            long long f = fBase + (long long)i * 64;
            if (f < total) {
                int le = leBase + i * 4;
                ((f4*)out)[f] = tbl[(int)cmb[le] * 16 + c];
            }
        }
    }
}

extern "C" void kernel_launch(void* const* d_in, const int* in_sizes, int n_in,
                              void* d_out, int out_size, void* d_ws, size_t ws_size,
                              hipStream_t stream) {
    const int* z     = (const int*)d_in[0];
    const int* src_g = (const int*)d_in[1];
    const int* dst_g = (const int*)d_in[2];
    const int* src_h = (const int*)d_in[3];
    const int* dst_h = (const int*)d_in[4];
    const int* src_i = (const int*)d_in[5];
    const int* dst_i = (const int*)d_in[6];
    const float* e1  = (const float*)d_in[7];
    const float* e2  = (const float*)d_in[8];
    const float* e3  = (const float*)d_in[9];
    const float* e4  = (const float*)d_in[10];
    const float* e5  = (const float*)d_in[11];
    const float* e6  = (const float*)d_in[12];

    int E_G = in_sizes[1];
    int E_H = in_sizes[3];
    int E_I = in_sizes[5];

    // Workspace: table | zg | zh | combo (256B-aligned)
    char* ws = (char*)d_ws;
    float* table = (float*)ws;
    size_t off   = 64 * N_FEAT * sizeof(float);
    unsigned short* zg = (unsigned short*)(ws + off);
    off += (size_t)E_G * sizeof(unsigned short);
    off  = (off + 255) & ~(size_t)255;
    unsigned short* zh = (unsigned short*)(ws + off);
    off += (size_t)E_H * sizeof(unsigned short);
    off  = (off + 255) & ~(size_t)255;
    unsigned char* combo = (unsigned char*)(ws + off);

    float* out = (float*)d_out;

    // K1: hop1 + table build
    {
        int n4 = E_G >> 2, nth = n4 + (E_G - (n4 << 2));
        int blocks = (nth + 255) / 256;
        if (blocks < 16) blocks = 16;
        hop1_table_kernel<<<blocks, 256, 0, stream>>>(z, src_g, dst_g, zg,
                                                      e1, e2, e3, e4, e5, e6,
                                                      table, E_G);
    }
    // K2
    {
        int n4 = E_H >> 2, nth = n4 + (E_H - (n4 << 2));
        hop2_kernel<<<(nth + 255) / 256, 256, 0, stream>>>(zg, src_h, dst_h, zh, E_H);
    }
    // K3a
    {
        int n4 = E_I >> 2, nth = n4 + (E_I - (n4 << 2));
        combo_kernel<<<(nth + 255) / 256, 256, 0, stream>>>(zh, src_i, dst_i, combo, E_I);
    }
    // K3b: fill-regime write, 4096 edges per block (~489 blocks)
    {
        int blocks = (E_I + WEPB - 1) / WEPB;
        write_kernel<<<blocks, 256, 0, stream>>>(combo, table, out, E_I);
    }
}

// Round 9
// 141.965 us; speedup vs baseline: 3.1107x; 1.0468x over previous
//
#include <hip/hip_runtime.h>

// ---------------------------------------------------------------------------
// color_invariant_quadruplet: 3-hop label gather + 6-way equality embedding sum
//
// The 6 equality bits take 64 combinations; each maps to a fixed 64-float row.
// Pipeline (3 one-shot kernels):
//   K1 : hop1 packed labels (8 edges/thread) + table build (blocks 0..15)
//   K2 : hop2 packed (z_ss, z_dd)            (8 edges/thread)
//   K3 : FUSED combo+write, WEPB=4096 edges/block (~489 blocks, all
//        co-resident at ~2/CU):
//          phase A: 16 edges/thread -> 32 outstanding zh gathers -> 16 combo
//                   bytes as one uint4 ds_write; table staged in parallel
//          barrier
//          phase B: r8's store loop verbatim (each wave owns a contiguous
//                   256KB stream, no global loads -> no vmcnt waits)
//
// Round 9: write path CLOSED (r3/r7/r8: three shapes all ~5.15 TB/s ~100us).
// This round attacks the measured ~48us gather+gap budget: fuse K3a into K3b
// (kill 1 gap + K3a dispatch + 4MB combo round-trip; 8x K3a's per-thread MLP)
// and double K1/K2 MLP to 8 edges/thread.
// ---------------------------------------------------------------------------

#define N_FEAT 64
#define WEPB   4096   // edges per write-block (1 MB output, 4 KB combo slice)

typedef float f4 __attribute__((ext_vector_type(4)));

// K1: hop1, 8 g-edges/thread (16 random z-gathers in flight); blocks 0..15
// also build the 64x64 table (reference left-to-right f32 order -> bit-exact).
__global__ void hop1_table_kernel(const int* __restrict__ z,
                                  const int* __restrict__ src_g,
                                  const int* __restrict__ dst_g,
                                  unsigned short* __restrict__ zg,
                                  const float* __restrict__ e1,
                                  const float* __restrict__ e2,
                                  const float* __restrict__ e3,
                                  const float* __restrict__ e4,
                                  const float* __restrict__ e5,
                                  const float* __restrict__ e6,
                                  float* __restrict__ table,
                                  int n) {
    int i  = blockIdx.x * blockDim.x + threadIdx.x;
    int n8 = n >> 3;
    if (i < n8) {
        const int4* s4 = (const int4*)src_g;
        const int4* d4 = (const int4*)dst_g;
        int4 sa = s4[2 * i], sb = s4[2 * i + 1];
        int4 da = d4[2 * i], db = d4[2 * i + 1];
        unsigned r0 = ((unsigned)z[sa.x] & 0xffu) | (((unsigned)z[da.x] & 0xffu) << 8)
                    | (((unsigned)z[sa.y] & 0xffu) << 16) | (((unsigned)z[da.y] & 0xffu) << 24);
        unsigned r1 = ((unsigned)z[sa.z] & 0xffu) | (((unsigned)z[da.z] & 0xffu) << 8)
                    | (((unsigned)z[sa.w] & 0xffu) << 16) | (((unsigned)z[da.w] & 0xffu) << 24);
        unsigned r2 = ((unsigned)z[sb.x] & 0xffu) | (((unsigned)z[db.x] & 0xffu) << 8)
                    | (((unsigned)z[sb.y] & 0xffu) << 16) | (((unsigned)z[db.y] & 0xffu) << 24);
        unsigned r3 = ((unsigned)z[sb.z] & 0xffu) | (((unsigned)z[db.z] & 0xffu) << 8)
                    | (((unsigned)z[sb.w] & 0xffu) << 16) | (((unsigned)z[db.w] & 0xffu) << 24);
        ((uint4*)zg)[i] = make_uint4(r0, r1, r2, r3);
    } else {
        int e = (n8 << 3) + (i - n8);      // tail edges, scalar
        if (e < n) {
            zg[e] = (unsigned short)(((unsigned)z[src_g[e]] & 0xffu)
                                   | (((unsigned)z[dst_g[e]] & 0xffu) << 8));
        }
    }
    if (blockIdx.x < 16) {
        int idx = blockIdx.x * 256 + threadIdx.x;   // 0..4095
        int cmb = idx >> 6;
        int f   = idx & (N_FEAT - 1);
        float v = e1[((cmb >> 0) & 1) * N_FEAT + f];
        v      += e2[((cmb >> 1) & 1) * N_FEAT + f];
        v      += e3[((cmb >> 2) & 1) * N_FEAT + f];
        v      += e4[((cmb >> 3) & 1) * N_FEAT + f];
        v      += e5[((cmb >> 4) & 1) * N_FEAT + f];
        v      += e6[((cmb >> 5) & 1) * N_FEAT + f];
        table[idx] = v;
    }
}

// K2: hop2, 8 h-edges/thread (16 random zg-gathers in flight).
// zh = z_src[src_h] | z_dst[dst_h]<<8.
__global__ void hop2_kernel(const unsigned short* __restrict__ zg,
                            const int* __restrict__ src_h,
                            const int* __restrict__ dst_h,
                            unsigned short* __restrict__ zh,
                            int n) {
    int i  = blockIdx.x * blockDim.x + threadIdx.x;
    int n8 = n >> 3;
    if (i < n8) {
        const int4* s4 = (const int4*)src_h;
        const int4* d4 = (const int4*)dst_h;
        int4 sa = s4[2 * i], sb = s4[2 * i + 1];
        int4 da = d4[2 * i], db = d4[2 * i + 1];
        unsigned a0 = zg[sa.x], b0 = zg[da.x];
        unsigned a1 = zg[sa.y], b1 = zg[da.y];
        unsigned a2 = zg[sa.z], b2 = zg[da.z];
        unsigned a3 = zg[sa.w], b3 = zg[da.w];
        unsigned a4 = zg[sb.x], b4 = zg[db.x];
        unsigned a5 = zg[sb.y], b5 = zg[db.y];
        unsigned a6 = zg[sb.z], b6 = zg[db.z];
        unsigned a7 = zg[sb.w], b7 = zg[db.w];
        unsigned r0 = (a0 & 0xffu) | (b0 & 0xff00u) | ((a1 & 0xffu) << 16) | ((b1 & 0xff00u) << 16);
        unsigned r1 = (a2 & 0xffu) | (b2 & 0xff00u) | ((a3 & 0xffu) << 16) | ((b3 & 0xff00u) << 16);
        unsigned r2 = (a4 & 0xffu) | (b4 & 0xff00u) | ((a5 & 0xffu) << 16) | ((b5 & 0xff00u) << 16);
        unsigned r3 = (a6 & 0xffu) | (b6 & 0xff00u) | ((a7 & 0xffu) << 16) | ((b7 & 0xff00u) << 16);
        ((uint4*)zh)[i] = make_uint4(r0, r1, r2, r3);
    } else {
        int e = (n8 << 3) + (i - n8);
        if (e < n) {
            unsigned a = zg[src_h[e]], b = zg[dst_h[e]];
            zh[e] = (unsigned short)((a & 0xffu) | (b & 0xff00u));
        }
    }
}

__device__ __forceinline__ unsigned combo6(unsigned p, unsigned q) {
    unsigned za = p & 0xffu, zc = p >> 8;
    unsigned zb = q & 0xffu, zd = q >> 8;
    return (unsigned)(za == zc)
         | ((unsigned)(za == zb) << 1)
         | ((unsigned)(zc == zb) << 2)
         | ((unsigned)(za == zd) << 3)
         | ((unsigned)(zc == zd) << 4)
         | ((unsigned)(zb == zd) << 5);
}

// K3: fused combo + fill-regime streaming write. WEPB=4096 edges (1 MB out)
// per block, ~489 blocks (all co-resident at ~2/CU).
// Phase A: thread t computes combo for local edges [16t,16t+16): 8 int4
//          index loads + 32 independent random zh gathers -> one uint4
//          ds_write. Table (16 KB) staged in parallel.
// Phase B: r8's store loop: wave w owns a contiguous 256 KB stream,
//          256 x {ds_read combo byte, ds_read_b128 table row, 1KB store};
//          no global loads -> stores never wait on vmcnt.
__global__ __launch_bounds__(256)
void fused_k3_kernel(const unsigned short* __restrict__ zh,
                     const int* __restrict__ src_i,
                     const int* __restrict__ dst_i,
                     const float* __restrict__ table,
                     float* __restrict__ out,
                     int nEdges) {
    __shared__ f4   tbl[64 * 16];          // 16 KB
    __shared__ uint4 cmbv[WEPB / 16];      // 4 KB of combo bytes
    const int tid = threadIdx.x;
    const long long e0 = (long long)blockIdx.x * WEPB;
    int nb = nEdges - (int)e0; if (nb > WEPB) nb = WEPB;

    // stage table (independent of combo path)
    const f4* t4 = (const f4*)table;
#pragma unroll
    for (int k = 0; k < 4; ++k)
        tbl[k * 256 + tid] = t4[k * 256 + tid];

    // phase A: 16 local edges per thread
    if (nb == WEPB) {
        const int4* si = (const int4*)(src_i + e0);
        const int4* di = (const int4*)(dst_i + e0);
        int4 s0 = si[tid * 4 + 0], s1 = si[tid * 4 + 1],
             s2 = si[tid * 4 + 2], s3 = si[tid * 4 + 3];
        int4 d0 = di[tid * 4 + 0], d1 = di[tid * 4 + 1],
             d2 = di[tid * 4 + 2], d3 = di[tid * 4 + 3];
        unsigned r0 =  combo6(zh[s0.x], zh[d0.x])
                    | (combo6(zh[s0.y], zh[d0.y]) << 8)
                    | (combo6(zh[s0.z], zh[d0.z]) << 16)
                    | (combo6(zh[s0.w], zh[d0.w]) << 24);
        unsigned r1 =  combo6(zh[s1.x], zh[d1.x])
                    | (combo6(zh[s1.y], zh[d1.y]) << 8)
                    | (combo6(zh[s1.z], zh[d1.z]) << 16)
                    | (combo6(zh[s1.w], zh[d1.w]) << 24);
        unsigned r2 =  combo6(zh[s2.x], zh[d2.x])
                    | (combo6(zh[s2.y], zh[d2.y]) << 8)
                    | (combo6(zh[s2.z], zh[d2.z]) << 16)
                    | (combo6(zh[s2.w], zh[d2.w]) << 24);
        unsigned r3 =  combo6(zh[s3.x], zh[d3.x])
                    | (combo6(zh[s3.y], zh[d3.y]) << 8)
                    | (combo6(zh[s3.z], zh[d3.z]) << 16)
                    | (combo6(zh[s3.w], zh[d3.w]) << 24);
        cmbv[tid] = make_uint4(r0, r1, r2, r3);
    } else {
        unsigned r[4] = {0u, 0u, 0u, 0u};
        for (int j = 0; j < 16; ++j) {
            int le = tid * 16 + j;
            if (le < nb) {
                long long e = e0 + le;
                unsigned c = combo6(zh[src_i[e]], zh[dst_i[e]]);
                r[j >> 2] |= c << ((j & 3) * 8);
            }
        }
        cmbv[tid] = make_uint4(r[0], r[1], r[2], r[3]);
    }
    __syncthreads();

    // phase B: wave w owns f4s [e0*16 + w*16384, +16384) -- contiguous 256 KB
    const unsigned char* cmb = (const unsigned char*)cmbv;
    const int  w      = tid >> 6;
    const int  lane   = tid & 63;
    const int  c      = lane & 15;
    const int  leBase = w * (WEPB / 4) + (lane >> 4);
    const long long fBase = e0 * 16 + (long long)w * (WEPB * 16 / 4) + lane;
    constexpr int ITER = WEPB * 16 / 4 / 64;            // 256

    if (nb == WEPB) {
#pragma unroll 4
        for (int i = 0; i < ITER; ++i) {
            int le = leBase + i * 4;
            ((f4*)out)[fBase + (long long)i * 64] = tbl[(int)cmb[le] * 16 + c];
        }
    } else {
        const long long total = (long long)nEdges * 16;
#pragma unroll 4
        for (int i = 0; i < ITER; ++i) {
            long long f = fBase + (long long)i * 64;
            if (f < total) {
                int le = leBase + i * 4;
                ((f4*)out)[f] = tbl[(int)cmb[le] * 16 + c];
            }
        }
    }
}

extern "C" void kernel_launch(void* const* d_in, const int* in_sizes, int n_in,
                              void* d_out, int out_size, void* d_ws, size_t ws_size,
                              hipStream_t stream) {
    const int* z     = (const int*)d_in[0];
    const int* src_g = (const int*)d_in[1];
    const int* dst_g = (const int*)d_in[2];
    const int* src_h = (const int*)d_in[3];
    const int* dst_h = (const int*)d_in[4];
    const int* src_i = (const int*)d_in[5];
    const int* dst_i = (const int*)d_in[6];
    const float* e1  = (const float*)d_in[7];
    const float* e2  = (const float*)d_in[8];
    const float* e3  = (const float*)d_in[9];
    const float* e4  = (const float*)d_in[10];
    const float* e5  = (const float*)d_in[11];
    const float* e6  = (const float*)d_in[12];

    int E_G = in_sizes[1];
    int E_H = in_sizes[3];
    int E_I = in_sizes[5];

    // Workspace: table | zg | zh (256B-aligned)
    char* ws = (char*)d_ws;
    float* table = (float*)ws;
    size_t off   = 64 * N_FEAT * sizeof(float);
    unsigned short* zg = (unsigned short*)(ws + off);
    off += (size_t)E_G * sizeof(unsigned short);
    off  = (off + 255) & ~(size_t)255;
    unsigned short* zh = (unsigned short*)(ws + off);

    float* out = (float*)d_out;

    // K1: hop1 (8 edges/thread) + table build
    {
        int n8 = E_G >> 3, nth = n8 + (E_G - (n8 << 3));
        int blocks = (nth + 255) / 256;
        if (blocks < 16) blocks = 16;
        hop1_table_kernel<<<blocks, 256, 0, stream>>>(z, src_g, dst_g, zg,
                                                      e1, e2, e3, e4, e5, e6,
                                                      table, E_G);
    }
    // K2: hop2 (8 edges/thread)
    {
        int n8 = E_H >> 3, nth = n8 + (E_H - (n8 << 3));
        hop2_kernel<<<(nth + 255) / 256, 256, 0, stream>>>(zg, src_h, dst_h, zh, E_H);
    }
    // K3: fused combo+write, 4096 edges per block
    {
        int blocks = (E_I + WEPB - 1) / WEPB;
        fused_k3_kernel<<<blocks, 256, 0, stream>>>(zh, src_i, dst_i, table, out, E_I);
    }
}